// Round 1
// baseline (194.332 us; speedup 1.0000x reference)
//
#include <hip/hip_runtime.h>
#include <hip/hip_bf16.h>

typedef __bf16 bf16_t;
typedef bf16_t bf16x8 __attribute__((ext_vector_type(8)));
typedef bf16_t bf16x4 __attribute__((ext_vector_type(4)));
typedef float f32x4 __attribute__((ext_vector_type(4)));

// ---------------------------------------------------------------------------
// convert f32 -> bf16, vectorized (float4 in, 4x bf16 out)
// ---------------------------------------------------------------------------
__global__ __launch_bounds__(256) void cvt_kernel(const float* __restrict__ in,
                                                  bf16_t* __restrict__ out, int n4) {
  int i = blockIdx.x * 256 + threadIdx.x;
  if (i >= n4) return;
  float4 v = reinterpret_cast<const float4*>(in)[i];
  bf16x4 o = { (bf16_t)v.x, (bf16_t)v.y, (bf16_t)v.z, (bf16_t)v.w };
  reinterpret_cast<bf16x4*>(out)[i] = o;
}

// ---------------------------------------------------------------------------
// transpose + convert: W[K][N] f32 -> Wt[N][K] bf16 (32x32 LDS tiles)
// ---------------------------------------------------------------------------
__global__ __launch_bounds__(256) void tcvt_kernel(const float* __restrict__ W,
                                                   bf16_t* __restrict__ Wt,
                                                   int K, int N) {
  __shared__ float tile[32][33];
  int tx = threadIdx.x & 31, ty = threadIdx.x >> 5;  // 32 x 8
  int n0 = blockIdx.x * 32, k0 = blockIdx.y * 32;
#pragma unroll
  for (int i = 0; i < 4; ++i)
    tile[ty + i * 8][tx] = W[(size_t)(k0 + ty + i * 8) * N + n0 + tx];
  __syncthreads();
#pragma unroll
  for (int i = 0; i < 4; ++i)
    Wt[(size_t)(n0 + ty + i * 8) * K + k0 + tx] = (bf16_t)tile[tx][ty + i * 8];
}

// ---------------------------------------------------------------------------
// GEMM: C[M][N] = A[M][K] @ Bt[N][K]^T + bias.  128x128 tile, BK=32,
// 4 waves (2x2), each wave 64x64 via 4x4 mfma_f32_16x16x32_bf16.
// Reg-staged global->LDS single buffer, prefetch next tile into regs.
// ---------------------------------------------------------------------------
template <int OUTF32>
__global__ __launch_bounds__(256) void gemm_bt_kernel(
    const bf16_t* __restrict__ A, const bf16_t* __restrict__ Bt,
    const float* __restrict__ bias, void* __restrict__ Cout,
    int M, int N, int K) {
  __shared__ __align__(16) bf16_t sA[128 * 32];
  __shared__ __align__(16) bf16_t sB[128 * 32];
  const int tid = threadIdx.x;
  const int l = tid & 63, w = tid >> 6;
  const int lr = l & 15, lg = l >> 4;
  const int m0 = blockIdx.y * 128, n0 = blockIdx.x * 128;
  const int wr = (w >> 1) * 64, wc = (w & 1) * 64;

  const int i0 = tid, i1 = tid + 256;
  const bf16_t* ga0 = A + (size_t)(m0 + (i0 >> 2)) * K + (i0 & 3) * 8;
  const bf16_t* ga1 = A + (size_t)(m0 + (i1 >> 2)) * K + (i1 & 3) * 8;
  const bf16_t* gb0 = Bt + (size_t)(n0 + (i0 >> 2)) * K + (i0 & 3) * 8;
  const bf16_t* gb1 = Bt + (size_t)(n0 + (i1 >> 2)) * K + (i1 & 3) * 8;

  f32x4 acc[4][4] = {};

  uint4 ra0 = *(const uint4*)ga0;
  uint4 ra1 = *(const uint4*)ga1;
  uint4 rb0 = *(const uint4*)gb0;
  uint4 rb1 = *(const uint4*)gb1;

  const int nk = K >> 5;
  for (int kt = 0; kt < nk; ++kt) {
    __syncthreads();  // previous iteration's readers done
    *(uint4*)&sA[i0 * 8] = ra0;
    *(uint4*)&sA[i1 * 8] = ra1;
    *(uint4*)&sB[i0 * 8] = rb0;
    *(uint4*)&sB[i1 * 8] = rb1;
    __syncthreads();  // tile visible
    if (kt + 1 < nk) {  // prefetch next tile into regs, overlaps MFMA below
      int ko = (kt + 1) * 32;
      ra0 = *(const uint4*)(ga0 + ko);
      ra1 = *(const uint4*)(ga1 + ko);
      rb0 = *(const uint4*)(gb0 + ko);
      rb1 = *(const uint4*)(gb1 + ko);
    }
    bf16x8 af[4], bv[4];
#pragma unroll
    for (int mf = 0; mf < 4; ++mf)
      af[mf] = *(const bf16x8*)&sA[(wr + mf * 16 + lr) * 32 + lg * 8];
#pragma unroll
    for (int nf = 0; nf < 4; ++nf)
      bv[nf] = *(const bf16x8*)&sB[(wc + nf * 16 + lr) * 32 + lg * 8];
#pragma unroll
    for (int mf = 0; mf < 4; ++mf)
#pragma unroll
      for (int nf = 0; nf < 4; ++nf)
        acc[mf][nf] = __builtin_amdgcn_mfma_f32_16x16x32_bf16(af[mf], bv[nf], acc[mf][nf], 0, 0, 0);
  }

  // epilogue: C row = (lane>>4)*4+reg, col = lane&15
#pragma unroll
  for (int mf = 0; mf < 4; ++mf) {
#pragma unroll
    for (int nf = 0; nf < 4; ++nf) {
      int col = n0 + wc + nf * 16 + lr;
      float bb = bias[col];
      int rowb = m0 + wr + mf * 16 + lg * 4;
#pragma unroll
      for (int r = 0; r < 4; ++r) {
        float v = acc[mf][nf][r] + bb;
        if constexpr (OUTF32)
          ((float*)Cout)[(size_t)(rowb + r) * N + col] = v;
        else
          ((bf16_t*)Cout)[(size_t)(rowb + r) * N + col] = (bf16_t)v;
      }
    }
  }
}

// ---------------------------------------------------------------------------
// Flash attention (both branches). Block = 4 waves x 32 q-rows = 128 q-rows.
// KV tiles of 64. K staged [kv][hd] XOR-swizzled; V staged transposed [hd][kv]
// XOR-swizzled; P goes through per-wave swizzled LDS (C-layout -> A-layout).
// scale 1/8 applied post-QK^T (exact). Causal mask == -1e30 (ref's -10000
// underflows identically after softmax).
// ---------------------------------------------------------------------------
__global__ __launch_bounds__(256) void attn_kernel(
    const bf16_t* __restrict__ qkv,    // [B*1024][3072], q at col h*64
    const bf16_t* __restrict__ kvsrc,  // [B*kv_len][kv_stride]
    bf16_t* __restrict__ obuf,         // [B*2048][1024] merged heads
    int kv_len, int kv_stride, int koff0, int voff0, int out_off, int causal) {
  __shared__ __align__(16) bf16_t sK[64 * 64];
  __shared__ __align__(16) bf16_t sV[64 * 64];
  __shared__ __align__(16) bf16_t sP[4][32 * 64];

  const int tid = threadIdx.x;
  const int l = tid & 63, w = tid >> 6;
  const int lr = l & 15, lg = l >> 4;
  const int qt = blockIdx.x, bh = blockIdx.y;
  const int b = bh >> 4, h = bh & 15;
  const int q0 = qt * 128;
  const int hcol = h * 64;
  const int qw = q0 + w * 32;

  // Q fragments resident: [mf][ks], A-layout row=lane&15, k=(lane>>4)*8+j
  bf16x8 qf[2][2];
#pragma unroll
  for (int mf = 0; mf < 2; ++mf)
#pragma unroll
    for (int ks = 0; ks < 2; ++ks)
      qf[mf][ks] = *(const bf16x8*)&qkv[(size_t)(b * 1024 + qw + mf * 16 + lr) * 3072 +
                                        hcol + ks * 32 + lg * 8];

  float mrun[8], lrun[8];
  f32x4 oacc[2][4] = {};
#pragma unroll
  for (int i = 0; i < 8; ++i) { mrun[i] = -1e30f; lrun[i] = 0.f; }

  const int nt = causal ? (q0 / 64 + 2) : (kv_len / 64);
  const int kvbase = b * kv_len;
  const int koff = koff0 + hcol, voff = voff0 + hcol;
  bf16_t* myP = &sP[w][0];

  for (int t = 0; t < nt; ++t) {
    const int kv0 = t * 64;
    __syncthreads();  // previous iteration's LDS readers done
#pragma unroll
    for (int c = 0; c < 2; ++c) {
      int i = tid + c * 256;
      // K: [kv][hd] swizzled, coalesced global reads
      int kr = i >> 3, kh8 = (i & 7) * 8;
      uint4 dk = *(const uint4*)&kvsrc[(size_t)(kvbase + kv0 + kr) * kv_stride + koff + kh8];
      int kb = (kr * 128 + kh8 * 2) ^ ((kr & 7) << 4);
      *(uint4*)((char*)sK + kb) = dk;
      // V: transpose to [hd][kv] swizzled (scatter writes, conflict-free mapping)
      int vr = i & 63, vh8 = (i >> 6) * 8;
      uint4 dv = *(const uint4*)&kvsrc[(size_t)(kvbase + kv0 + vr) * kv_stride + voff + vh8];
      const bf16_t* pv = (const bf16_t*)&dv;
#pragma unroll
      for (int j = 0; j < 8; ++j) {
        int hd = vh8 + j;
        int vb = (hd * 128 + vr * 2) ^ ((hd & 7) << 4);
        *(bf16_t*)((char*)sV + vb) = pv[j];
      }
    }
    __syncthreads();

    // S = Q @ K^T
    f32x4 s[2][4] = {};
#pragma unroll
    for (int ks = 0; ks < 2; ++ks) {
#pragma unroll
      for (int nf = 0; nf < 4; ++nf) {
        int kvr = nf * 16 + lr;
        int bo = (kvr * 128 + ks * 64 + lg * 16) ^ ((kvr & 7) << 4);
        bf16x8 kf = *(const bf16x8*)((char*)sK + bo);
#pragma unroll
        for (int mf = 0; mf < 2; ++mf)
          s[mf][nf] = __builtin_amdgcn_mfma_f32_16x16x32_bf16(qf[mf][ks], kf, s[mf][nf], 0, 0, 0);
      }
    }

    // online softmax; each lane owns 8 q-rows (mf x r), cols = nf*16+lr
#pragma unroll
    for (int mf = 0; mf < 2; ++mf) {
#pragma unroll
      for (int r = 0; r < 4; ++r) {
        const int i = mf * 4 + r;
        const int qrow = qw + mf * 16 + lg * 4 + r;
        float tm = -1e30f;
#pragma unroll
        for (int nf = 0; nf < 4; ++nf) {
          float v = s[mf][nf][r] * 0.125f;
          if (causal && (kv0 + nf * 16 + lr > qrow)) v = -1e30f;
          s[mf][nf][r] = v;
          tm = fmaxf(tm, v);
        }
#pragma unroll
        for (int d = 1; d < 16; d <<= 1) tm = fmaxf(tm, __shfl_xor(tm, d));
        float mn = fmaxf(mrun[i], tm);
        float sc = __expf(mrun[i] - mn);
        mrun[i] = mn;
        float ps = 0.f;
#pragma unroll
        for (int nf = 0; nf < 4; ++nf) {
          float p = __expf(s[mf][nf][r] - mn);
          s[mf][nf][r] = p;
          ps += p;
        }
#pragma unroll
        for (int d = 1; d < 16; d <<= 1) ps += __shfl_xor(ps, d);
        lrun[i] = lrun[i] * sc + ps;
#pragma unroll
        for (int nf = 0; nf < 4; ++nf) oacc[mf][nf][r] *= sc;
      }
    }

    // P (C-layout) -> per-wave LDS (swizzled) -> A-layout fragments
#pragma unroll
    for (int mf = 0; mf < 2; ++mf)
#pragma unroll
      for (int nf = 0; nf < 4; ++nf)
#pragma unroll
        for (int r = 0; r < 4; ++r) {
          int qr = mf * 16 + lg * 4 + r;
          int bo = (qr * 128 + (nf * 16 + lr) * 2) ^ ((qr & 7) << 4);
          *(bf16_t*)((char*)myP + bo) = (bf16_t)s[mf][nf][r];
        }

    // O += P @ V
#pragma unroll
    for (int ks = 0; ks < 2; ++ks) {
      bf16x8 pa[2];
#pragma unroll
      for (int mf = 0; mf < 2; ++mf) {
        int qr = mf * 16 + lr;
        int bo = (qr * 128 + ks * 64 + lg * 16) ^ ((qr & 7) << 4);
        pa[mf] = *(const bf16x8*)((char*)myP + bo);
      }
#pragma unroll
      for (int nf = 0; nf < 4; ++nf) {
        int hd = nf * 16 + lr;
        int bo = (hd * 128 + ks * 64 + lg * 16) ^ ((hd & 7) << 4);
        bf16x8 vv = *(const bf16x8*)((char*)sV + bo);
#pragma unroll
        for (int mf = 0; mf < 2; ++mf)
          oacc[mf][nf] = __builtin_amdgcn_mfma_f32_16x16x32_bf16(pa[mf], vv, oacc[mf][nf], 0, 0, 0);
      }
    }
  }

  // normalize + write merged heads (bf16)
  const int orow = b * 2048 + out_off + qw;
#pragma unroll
  for (int mf = 0; mf < 2; ++mf)
#pragma unroll
    for (int nf = 0; nf < 4; ++nf)
#pragma unroll
      for (int r = 0; r < 4; ++r) {
        float v = oacc[mf][nf][r] / lrun[mf * 4 + r];
        obuf[(size_t)(orow + mf * 16 + lg * 4 + r) * 1024 + hcol + nf * 16 + lr] = (bf16_t)v;
      }
}

// ---------------------------------------------------------------------------
extern "C" void kernel_launch(void* const* d_in, const int* in_sizes, int n_in,
                              void* d_out, int out_size, void* d_ws, size_t ws_size,
                              hipStream_t stream) {
  (void)in_sizes; (void)n_in; (void)out_size; (void)ws_size;
  const float* x   = (const float*)d_in[0];
  const float* pkg = (const float*)d_in[1];
  const float* Wc  = (const float*)d_in[2];
  const float* bc  = (const float*)d_in[3];
  const float* Wk  = (const float*)d_in[4];
  const float* bk  = (const float*)d_in[5];
  const float* Wp  = (const float*)d_in[6];
  const float* bp  = (const float*)d_in[7];
  float* out = (float*)d_out;

  char* ws = (char*)d_ws;
  const size_t MB = 1u << 20;
  bf16_t* xb   = (bf16_t*)(ws + 0 * MB);   // [4096][1024]   8 MB
  bf16_t* pkb  = (bf16_t*)(ws + 8 * MB);   // [1024][1024]   2 MB
  bf16_t* Wct  = (bf16_t*)(ws + 10 * MB);  // [3072][1024]   6 MB
  bf16_t* Wkt  = (bf16_t*)(ws + 16 * MB);  // [2048][1024]   4 MB
  bf16_t* Wpt  = (bf16_t*)(ws + 20 * MB);  // [1024][1024]   2 MB
  bf16_t* kkvb = (bf16_t*)(ws + 22 * MB);  // [1024][2048]   4 MB
  bf16_t* abuf = (bf16_t*)(ws + 26 * MB);  // [8192][1024]  16 MB  (total ws: 42 MB)
  // qkv intermediate lives in d_out (24 of 32 MB); fully overwritten by final GEMM
  bf16_t* qkvb = (bf16_t*)d_out;           // [4096][3072]  24 MB

  cvt_kernel<<<4096, 256, 0, stream>>>(x, xb, 4096 * 1024 / 4);
  cvt_kernel<<<1024, 256, 0, stream>>>(pkg, pkb, 1024 * 1024 / 4);
  tcvt_kernel<<<dim3(3072 / 32, 1024 / 32), 256, 0, stream>>>(Wc, Wct, 1024, 3072);
  tcvt_kernel<<<dim3(2048 / 32, 1024 / 32), 256, 0, stream>>>(Wk, Wkt, 1024, 2048);
  tcvt_kernel<<<dim3(1024 / 32, 1024 / 32), 256, 0, stream>>>(Wp, Wpt, 1024, 1024);

  // qkv = x @ Wc + bc  -> bf16 [4096][3072]
  gemm_bt_kernel<0><<<dim3(3072 / 128, 4096 / 128), 256, 0, stream>>>(xb, Wct, bc, qkvb, 4096, 3072, 1024);
  // kkv = pred_kg @ Wk + bk -> bf16 [1024][2048]
  gemm_bt_kernel<0><<<dim3(2048 / 128, 1024 / 128), 256, 0, stream>>>(pkb, Wkt, bk, kkvb, 1024, 2048, 1024);

  // self-attn (causal): q,k,v from qkv; out rows b*2048 + s
  attn_kernel<<<dim3(8, 64), 256, 0, stream>>>(qkvb, qkvb, abuf, 1024, 3072, 1024, 2048, 0, 1);
  // cross-attn: k,v from kkv; out rows b*2048 + 1024 + s
  attn_kernel<<<dim3(8, 64), 256, 0, stream>>>(qkvb, kkvb, abuf, 256, 2048, 0, 1024, 1024, 0);

  // out = [a; ka] @ Wp + bp -> f32 d_out (identity row mapping)
  gemm_bt_kernel<1><<<dim3(1024 / 128, 8192 / 128), 256, 0, stream>>>(abuf, Wpt, bp, out, 8192, 1024, 1024);
}

// Round 2
// 176.382 us; speedup vs baseline: 1.1018x; 1.1018x over previous
//
#include <hip/hip_runtime.h>
#include <hip/hip_bf16.h>

typedef __bf16 bf16_t;
typedef bf16_t bf16x8 __attribute__((ext_vector_type(8)));
typedef bf16_t bf16x4 __attribute__((ext_vector_type(4)));
typedef float f32x4 __attribute__((ext_vector_type(4)));
typedef float f32x16 __attribute__((ext_vector_type(16)));

// async global->LDS, 16B per lane (dest must be wave-uniform base + lane*16)
__device__ __forceinline__ void gload16(const void* g, void* l) {
  __builtin_amdgcn_global_load_lds(
      (const __attribute__((address_space(1))) void*)g,
      (__attribute__((address_space(3))) void*)l, 16, 0, 0);
}

__device__ __forceinline__ unsigned pkbf(float lo, float hi) {
  unsigned short a = __builtin_bit_cast(unsigned short, (bf16_t)lo);
  unsigned short b = __builtin_bit_cast(unsigned short, (bf16_t)hi);
  return (unsigned)a | ((unsigned)b << 16);
}

// ---------------------------------------------------------------------------
// convert f32 -> bf16, vectorized
// ---------------------------------------------------------------------------
__global__ __launch_bounds__(256) void cvt_kernel(const float* __restrict__ in,
                                                  bf16_t* __restrict__ out, int n4) {
  int i = blockIdx.x * 256 + threadIdx.x;
  if (i >= n4) return;
  float4 v = reinterpret_cast<const float4*>(in)[i];
  bf16x4 o = { (bf16_t)v.x, (bf16_t)v.y, (bf16_t)v.z, (bf16_t)v.w };
  reinterpret_cast<bf16x4*>(out)[i] = o;
}

// ---------------------------------------------------------------------------
// transpose + convert: W[K][N] f32 -> Wt[N][K] bf16
// ---------------------------------------------------------------------------
__global__ __launch_bounds__(256) void tcvt_kernel(const float* __restrict__ W,
                                                   bf16_t* __restrict__ Wt,
                                                   int K, int N) {
  __shared__ float tile[32][33];
  int tx = threadIdx.x & 31, ty = threadIdx.x >> 5;
  int n0 = blockIdx.x * 32, k0 = blockIdx.y * 32;
#pragma unroll
  for (int i = 0; i < 4; ++i)
    tile[ty + i * 8][tx] = W[(size_t)(k0 + ty + i * 8) * N + n0 + tx];
  __syncthreads();
#pragma unroll
  for (int i = 0; i < 4; ++i)
    Wt[(size_t)(n0 + ty + i * 8) * K + k0 + tx] = (bf16_t)tile[tx][ty + i * 8];
}

// ---------------------------------------------------------------------------
// V transpose per head: src[b*R + s][stride] cols (coloff + h*64 + d)
//   -> vT[(bh*64 + d)*R + s]
// ---------------------------------------------------------------------------
__global__ __launch_bounds__(256) void vtrans_kernel(const bf16_t* __restrict__ src,
                                                     bf16_t* __restrict__ vT,
                                                     int R, int stride, int coloff) {
  __shared__ bf16_t tile[64][72];  // row stride 144B (16B-aligned)
  const int tid = threadIdx.x;
  const int bh = blockIdx.y, s0 = blockIdx.x * 64;
  const int b = bh >> 4, h = bh & 15;
#pragma unroll
  for (int it = 0; it < 2; ++it) {
    int idx = it * 256 + tid;
    int r = idx >> 3, c8 = idx & 7;
    *(bf16x8*)&tile[r][c8 * 8] =
        *(const bf16x8*)&src[(size_t)(b * R + s0 + r) * stride + coloff + h * 64 + c8 * 8];
  }
  __syncthreads();
#pragma unroll
  for (int it = 0; it < 2; ++it) {
    int idx = it * 256 + tid;
    int d = idx >> 3, ch = idx & 7;
    bf16x8 o;
#pragma unroll
    for (int j = 0; j < 8; ++j) o[j] = tile[ch * 8 + j][d];
    *(bf16x8*)&vT[(size_t)(bh * 64 + d) * R + s0 + ch * 8] = o;
  }
}

// ---------------------------------------------------------------------------
// GEMM: C[M][N] = A[M][K] @ Bt[N][K]^T + bias.  128x128 tile, BK=32,
// 4 waves, 4x4 mfma_f32_16x16x32_bf16 per wave. global_load_lds staging.
// ---------------------------------------------------------------------------
template <int OUTF32>
__global__ __launch_bounds__(256) void gemm_bt_kernel(
    const bf16_t* __restrict__ A, const bf16_t* __restrict__ Bt,
    const float* __restrict__ bias, void* __restrict__ Cout,
    int M, int N, int K) {
  __shared__ __align__(16) bf16_t sA[128 * 32];
  __shared__ __align__(16) bf16_t sB[128 * 32];
  const int tid = threadIdx.x;
  const int l = tid & 63, w = tid >> 6;
  const int lr = l & 15, lg = l >> 4;
  const int m0 = blockIdx.y * 128, n0 = blockIdx.x * 128;
  const int wr = (w >> 1) * 64, wc = (w & 1) * 64;

  const int i0 = tid, i1 = tid + 256;
  const bf16_t* ga0 = A + (size_t)(m0 + (i0 >> 2)) * K + (i0 & 3) * 8;
  const bf16_t* ga1 = A + (size_t)(m0 + (i1 >> 2)) * K + (i1 & 3) * 8;
  const bf16_t* gb0 = Bt + (size_t)(n0 + (i0 >> 2)) * K + (i0 & 3) * 8;
  const bf16_t* gb1 = Bt + (size_t)(n0 + (i1 >> 2)) * K + (i1 & 3) * 8;

  f32x4 acc[4][4] = {};

  const int nk = K >> 5;
  for (int kt = 0; kt < nk; ++kt) {
    const int ko = kt * 32;
    __syncthreads();  // previous iteration's readers done
    gload16(ga0 + ko, &sA[i0 * 8]);
    gload16(ga1 + ko, &sA[i1 * 8]);
    gload16(gb0 + ko, &sB[i0 * 8]);
    gload16(gb1 + ko, &sB[i1 * 8]);
    __syncthreads();  // vmcnt(0) drained before barrier -> tile visible
    bf16x8 af[4], bv[4];
#pragma unroll
    for (int mf = 0; mf < 4; ++mf)
      af[mf] = *(const bf16x8*)&sA[(wr + mf * 16 + lr) * 32 + lg * 8];
#pragma unroll
    for (int nf = 0; nf < 4; ++nf)
      bv[nf] = *(const bf16x8*)&sB[(wc + nf * 16 + lr) * 32 + lg * 8];
#pragma unroll
    for (int mf = 0; mf < 4; ++mf)
#pragma unroll
      for (int nf = 0; nf < 4; ++nf)
        acc[mf][nf] = __builtin_amdgcn_mfma_f32_16x16x32_bf16(af[mf], bv[nf], acc[mf][nf], 0, 0, 0);
  }

#pragma unroll
  for (int mf = 0; mf < 4; ++mf) {
#pragma unroll
    for (int nf = 0; nf < 4; ++nf) {
      int col = n0 + wc + nf * 16 + lr;
      float bb = bias[col];
      int rowb = m0 + wr + mf * 16 + lg * 4;
#pragma unroll
      for (int r = 0; r < 4; ++r) {
        float v = acc[mf][nf][r] + bb;
        if constexpr (OUTF32)
          ((float*)Cout)[(size_t)(rowb + r) * N + col] = v;
        else
          ((bf16_t*)Cout)[(size_t)(rowb + r) * N + col] = (bf16_t)v;
      }
    }
  }
}

// ---------------------------------------------------------------------------
// Unified flash attention, barrier-free main loop.
// One wave = one 32-row q-tile of one (b,h), both branches in one launch.
// Swapped QK^T (mfma(K,Q)): lane owns q-row = lane&31. KVBLK=32.
// All operands direct-from-global (L2-resident). P stays in registers.
// ---------------------------------------------------------------------------
__global__ __launch_bounds__(256, 2) void attn_kernel(
    const bf16_t* __restrict__ qkv,   // [4096][3072] (q at hcol, k at 1024+hcol, v at 2048+hcol)
    const bf16_t* __restrict__ kkv,   // [1024][2048] (kk at hcol, kv at 1024+hcol)
    const bf16_t* __restrict__ vTs,   // [64][64][1024]  self V^T
    const bf16_t* __restrict__ vTc,   // [64][64][256]   cross V^T
    bf16_t* __restrict__ obuf) {      // [8192][1024]
  __shared__ __align__(16) char swb[4][4096];

  const int tid = threadIdx.x;
  const int w = tid >> 6, l = tid & 63;
  const int ql = l & 31;
  const bool uhi = l >= 32;
  const int hi8 = uhi ? 8 : 0;
  const int kv4 = uhi ? 4 : 0;

  const bool is_self = (w < 2);
  const int js = blockIdx.x + (w & 1) * 1024;
  int bh, qt, nt;
  if (is_self) {
    bh = js >> 5;
    int qraw = js & 31;
    qt = ((js >> 10) & 1) ? 31 - qraw : qraw;
    nt = qt + 1;
  } else {
    bh = js >> 5;
    qt = js & 31;
    nt = 8;
  }
  const int b = bh >> 4, h = bh & 15;
  const int hcol = h * 64;
  const int q0 = qt * 32;

  const bf16_t* ksrc;
  const bf16_t* vsrc;
  int kstride, kvb, vlen, ooff;
  if (is_self) {
    ksrc = qkv + 1024 + hcol; kstride = 3072; kvb = b * 1024;
    vsrc = vTs + (size_t)bh * 64 * 1024; vlen = 1024; ooff = 0;
  } else {
    ksrc = kkv + hcol; kstride = 2048; kvb = b * 256;
    vsrc = vTc + (size_t)bh * 64 * 256; vlen = 256; ooff = 1024;
  }

  // Q fragments (B-operand): lane holds col q = ql, k = hd = ks*16 + hi8 + j
  const bf16_t* qrow = qkv + (size_t)(b * 1024 + q0 + ql) * 3072 + hcol + hi8;
  bf16x8 qf[4];
#pragma unroll
  for (int ks = 0; ks < 4; ++ks) qf[ks] = *(const bf16x8*)(qrow + ks * 16);

  float mcur = -1e30f, lcur = 0.f;
  f32x16 oacc[2] = {};

  for (int t = 0; t < nt; ++t) {
    const int kv0 = t * 32;
    // K fragments (A-operand): lane holds row kv = ql, k = hd
    const bf16_t* kr = ksrc + (size_t)(kvb + kv0 + ql) * kstride + hi8;
    bf16x8 kf[4];
#pragma unroll
    for (int ks = 0; ks < 4; ++ks) kf[ks] = *(const bf16x8*)(kr + ks * 16);
    // V^T fragments (A-operand of PV): lane holds row hd = mb*32+ql, k = kv
    bf16x8 vf[2][2];
#pragma unroll
    for (int mb = 0; mb < 2; ++mb)
#pragma unroll
      for (int ks = 0; ks < 2; ++ks)
        vf[mb][ks] = *(const bf16x8*)(vsrc + (size_t)(mb * 32 + ql) * vlen + kv0 + ks * 16 + hi8);

    // S^T = K @ Q^T : C col = q = ql, row = kv = (r&3)+8*(r>>2)+kv4
    f32x16 sa = {};
#pragma unroll
    for (int ks = 0; ks < 4; ++ks)
      sa = __builtin_amdgcn_mfma_f32_32x32x16_bf16(kf[ks], qf[ks], sa, 0, 0, 0);

    float sv[16];
    const bool mt = is_self && (t == qt);  // diagonal tile
#pragma unroll
    for (int r = 0; r < 16; ++r) {
      float v = sa[r] * 0.125f;
      if (mt) {
        int kvr = (r & 3) + 8 * (r >> 2) + kv4;
        v = (kvr > ql) ? -1e30f : v;
      }
      sv[r] = v;
    }
    float tm = fmaxf(
        fmaxf(fmaxf(fmaxf(sv[0], sv[1]), fmaxf(sv[2], sv[3])),
              fmaxf(fmaxf(sv[4], sv[5]), fmaxf(sv[6], sv[7]))),
        fmaxf(fmaxf(fmaxf(sv[8], sv[9]), fmaxf(sv[10], sv[11])),
              fmaxf(fmaxf(sv[12], sv[13]), fmaxf(sv[14], sv[15]))));
    tm = fmaxf(tm, __shfl_xor(tm, 32));

    if (!__all(tm <= mcur + 8.f)) {  // defer-max: skip rescale when growth small
      float mn = fmaxf(mcur, tm);
      float sc = __expf(mcur - mn);
      mcur = mn;
      lcur *= sc;
#pragma unroll
      for (int mb = 0; mb < 2; ++mb)
#pragma unroll
        for (int r = 0; r < 16; ++r) oacc[mb][r] *= sc;
    }

    float pf[16];
#pragma unroll
    for (int r = 0; r < 16; ++r) pf[r] = __expf(sv[r] - mcur);
    float ps = (((pf[0] + pf[1]) + (pf[2] + pf[3])) + ((pf[4] + pf[5]) + (pf[6] + pf[7]))) +
               (((pf[8] + pf[9]) + (pf[10] + pf[11])) + ((pf[12] + pf[13]) + (pf[14] + pf[15])));
    ps += __shfl_xor(ps, 32);
    lcur += ps;

    // P -> PV B-fragments, in-register (pack + half-wave exchange + select)
    unsigned o01 = pkbf(pf[0], pf[1]), o23 = pkbf(pf[2], pf[3]);
    unsigned o45 = pkbf(pf[4], pf[5]), o67 = pkbf(pf[6], pf[7]);
    unsigned o89 = pkbf(pf[8], pf[9]), o1011 = pkbf(pf[10], pf[11]);
    unsigned o1213 = pkbf(pf[12], pf[13]), o1415 = pkbf(pf[14], pf[15]);
    unsigned p01 = __shfl_xor(o01, 32), p23 = __shfl_xor(o23, 32);
    unsigned p45 = __shfl_xor(o45, 32), p67 = __shfl_xor(o67, 32);
    unsigned p89 = __shfl_xor(o89, 32), p1011 = __shfl_xor(o1011, 32);
    unsigned p1213 = __shfl_xor(o1213, 32), p1415 = __shfl_xor(o1415, 32);
    uint4 w0 = { uhi ? p45 : o01, uhi ? p67 : o23, uhi ? o45 : p01, uhi ? o67 : p23 };
    uint4 w1 = { uhi ? p1213 : o89, uhi ? p1415 : o1011, uhi ? o1213 : p89, uhi ? o1415 : p1011 };
    bf16x8 pb0 = __builtin_bit_cast(bf16x8, w0);
    bf16x8 pb1 = __builtin_bit_cast(bf16x8, w1);

    // O^T += V^T @ P : C col = q = ql, row = hd
#pragma unroll
    for (int mb = 0; mb < 2; ++mb) {
      oacc[mb] = __builtin_amdgcn_mfma_f32_32x32x16_bf16(vf[mb][0], pb0, oacc[mb], 0, 0, 0);
      oacc[mb] = __builtin_amdgcn_mfma_f32_32x32x16_bf16(vf[mb][1], pb1, oacc[mb], 0, 0, 0);
    }
  }

  // epilogue: normalize, transpose O^T -> O via per-wave LDS, coalesced store
  const float rl = 1.0f / lcur;
  char* swp = &swb[w][0];
#pragma unroll
  for (int mb = 0; mb < 2; ++mb)
#pragma unroll
    for (int r2 = 0; r2 < 8; ++r2) {
      float lo = oacc[mb][2 * r2] * rl;
      float hiv = oacc[mb][2 * r2 + 1] * rl;
      int hdb = (r2 & 1) * 2 + 8 * (r2 >> 1) + kv4 + mb * 32;
      int off = (ql * 128 + hdb * 2) ^ ((ql & 7) << 4);
      *(unsigned*)(swp + off) = pkbf(lo, hiv);
    }
  __syncthreads();  // intra-wave LDS drain (also joins waves; harmless)
  const int orow = b * 2048 + ooff + q0;
#pragma unroll
  for (int it = 0; it < 4; ++it) {
    int idx = it * 64 + l;
    int q = idx >> 3, ch = idx & 7;
    int off = (q * 128 + ch * 16) ^ ((q & 7) << 4);
    uint4 d = *(uint4*)(swp + off);
    *(uint4*)&obuf[(size_t)(orow + q) * 1024 + hcol + ch * 8] = d;
  }
}

// ---------------------------------------------------------------------------
extern "C" void kernel_launch(void* const* d_in, const int* in_sizes, int n_in,
                              void* d_out, int out_size, void* d_ws, size_t ws_size,
                              hipStream_t stream) {
  (void)in_sizes; (void)n_in; (void)out_size; (void)ws_size;
  const float* x   = (const float*)d_in[0];
  const float* pkg = (const float*)d_in[1];
  const float* Wc  = (const float*)d_in[2];
  const float* bc  = (const float*)d_in[3];
  const float* Wk  = (const float*)d_in[4];
  const float* bk  = (const float*)d_in[5];
  const float* Wp  = (const float*)d_in[6];
  const float* bp  = (const float*)d_in[7];
  float* out = (float*)d_out;

  char* ws = (char*)d_ws;
  const size_t MB = 1u << 20;
  bf16_t* xb   = (bf16_t*)(ws + 0 * MB);   // [4096][1024]   8 MB
  bf16_t* pkb  = (bf16_t*)(ws + 8 * MB);   // [1024][1024]   2 MB
  bf16_t* Wct  = (bf16_t*)(ws + 10 * MB);  // [3072][1024]   6 MB
  bf16_t* Wkt  = (bf16_t*)(ws + 16 * MB);  // [2048][1024]   4 MB
  bf16_t* Wpt  = (bf16_t*)(ws + 20 * MB);  // [1024][1024]   2 MB
  bf16_t* kkvb = (bf16_t*)(ws + 22 * MB);  // [1024][2048]   4 MB
  bf16_t* abuf = (bf16_t*)(ws + 26 * MB);  // [8192][1024]  16 MB
  bf16_t* vTc  = (bf16_t*)(ws + 42 * MB);  // [64][64][256]  2 MB (ws total 44 MB)
  // d_out double-duty: qkv intermediate + self V^T; both dead before proj GEMM
  bf16_t* qkvb = (bf16_t*)d_out;                      // [4096][3072] 24 MB
  bf16_t* vTs  = (bf16_t*)((char*)d_out + 24 * MB);   // [64][64][1024] 8 MB

  cvt_kernel<<<4096, 256, 0, stream>>>(x, xb, 4096 * 1024 / 4);
  cvt_kernel<<<1024, 256, 0, stream>>>(pkg, pkb, 1024 * 1024 / 4);
  tcvt_kernel<<<dim3(3072 / 32, 1024 / 32), 256, 0, stream>>>(Wc, Wct, 1024, 3072);
  tcvt_kernel<<<dim3(2048 / 32, 1024 / 32), 256, 0, stream>>>(Wk, Wkt, 1024, 2048);
  tcvt_kernel<<<dim3(1024 / 32, 1024 / 32), 256, 0, stream>>>(Wp, Wpt, 1024, 1024);

  gemm_bt_kernel<0><<<dim3(24, 32), 256, 0, stream>>>(xb, Wct, bc, qkvb, 4096, 3072, 1024);
  gemm_bt_kernel<0><<<dim3(16, 8), 256, 0, stream>>>(pkb, Wkt, bk, kkvb, 1024, 2048, 1024);

  vtrans_kernel<<<dim3(16, 64), 256, 0, stream>>>(qkvb, vTs, 1024, 3072, 2048);
  vtrans_kernel<<<dim3(4, 64), 256, 0, stream>>>(kkvb, vTc, 256, 2048, 1024);

  attn_kernel<<<dim3(1024), 256, 0, stream>>>(qkvb, kkvb, vTs, vTc, abuf);

  gemm_bt_kernel<1><<<dim3(8, 64), 256, 0, stream>>>(abuf, Wpt, bp, out, 8192, 1024, 1024);
}

// Round 4
// 171.690 us; speedup vs baseline: 1.1319x; 1.0273x over previous
//
#include <hip/hip_runtime.h>
#include <hip/hip_bf16.h>

typedef __bf16 bf16_t;
typedef bf16_t bf16x8 __attribute__((ext_vector_type(8)));
typedef bf16_t bf16x4 __attribute__((ext_vector_type(4)));
typedef float f32x4 __attribute__((ext_vector_type(4)));
typedef float f32x16 __attribute__((ext_vector_type(16)));

#define EXP2C 0.1803368867f  // 0.125 * log2(e)
#define FEXP2(x) __builtin_amdgcn_exp2f(x)  // v_exp_f32 (base-2)

// async global->LDS, 16B per lane (dest must be wave-uniform base + lane*16)
__device__ __forceinline__ void gload16(const void* g, void* l) {
  __builtin_amdgcn_global_load_lds(
      (const __attribute__((address_space(1))) void*)g,
      (__attribute__((address_space(3))) void*)l, 16, 0, 0);
}

__device__ __forceinline__ unsigned pkbf(float lo, float hi) {
  unsigned short a = __builtin_bit_cast(unsigned short, (bf16_t)lo);
  unsigned short b = __builtin_bit_cast(unsigned short, (bf16_t)hi);
  return (unsigned)a | ((unsigned)b << 16);
}

// ---------------------------------------------------------------------------
// convert f32 -> bf16, vectorized
// ---------------------------------------------------------------------------
__global__ __launch_bounds__(256) void cvt_kernel(const float* __restrict__ in,
                                                  bf16_t* __restrict__ out, int n4) {
  int i = blockIdx.x * 256 + threadIdx.x;
  if (i >= n4) return;
  float4 v = reinterpret_cast<const float4*>(in)[i];
  bf16x4 o = { (bf16_t)v.x, (bf16_t)v.y, (bf16_t)v.z, (bf16_t)v.w };
  reinterpret_cast<bf16x4*>(out)[i] = o;
}

// ---------------------------------------------------------------------------
// transpose + convert: W[K][N] f32 -> Wt[N][K] bf16
// ---------------------------------------------------------------------------
__global__ __launch_bounds__(256) void tcvt_kernel(const float* __restrict__ W,
                                                   bf16_t* __restrict__ Wt,
                                                   int K, int N) {
  __shared__ float tile[32][33];
  int tx = threadIdx.x & 31, ty = threadIdx.x >> 5;
  int n0 = blockIdx.x * 32, k0 = blockIdx.y * 32;
#pragma unroll
  for (int i = 0; i < 4; ++i)
    tile[ty + i * 8][tx] = W[(size_t)(k0 + ty + i * 8) * N + n0 + tx];
  __syncthreads();
#pragma unroll
  for (int i = 0; i < 4; ++i)
    Wt[(size_t)(n0 + ty + i * 8) * K + k0 + tx] = (bf16_t)tile[tx][ty + i * 8];
}

// ---------------------------------------------------------------------------
// V transpose per head: src[b*R + s][stride] cols (coloff + h*64 + d)
//   -> vT[(bh*64 + d)*R + s]
// ---------------------------------------------------------------------------
__global__ __launch_bounds__(256) void vtrans_kernel(const bf16_t* __restrict__ src,
                                                     bf16_t* __restrict__ vT,
                                                     int R, int stride, int coloff) {
  __shared__ bf16_t tile[64][72];
  const int tid = threadIdx.x;
  const int bh = blockIdx.y, s0 = blockIdx.x * 64;
  const int b = bh >> 4, h = bh & 15;
#pragma unroll
  for (int it = 0; it < 2; ++it) {
    int idx = it * 256 + tid;
    int r = idx >> 3, c8 = idx & 7;
    *(bf16x8*)&tile[r][c8 * 8] =
        *(const bf16x8*)&src[(size_t)(b * R + s0 + r) * stride + coloff + h * 64 + c8 * 8];
  }
  __syncthreads();
#pragma unroll
  for (int it = 0; it < 2; ++it) {
    int idx = it * 256 + tid;
    int d = idx >> 3, ch = idx & 7;
    bf16x8 o;
#pragma unroll
    for (int j = 0; j < 8; ++j) o[j] = tile[ch * 8 + j][d];
    *(bf16x8*)&vT[(size_t)(bh * 64 + d) * R + s0 + ch * 8] = o;
  }
}

// ---------------------------------------------------------------------------
// GEMM: C[M][N] = A[M][K] @ Bt[N][K]^T + bias.  128x128 tile, BK=32,
// 4 waves, 4x4 mfma_f32_16x16x32_bf16. 2-phase double-buffered
// global_load_lds staging (issue next-tile STAGE before current compute).
// ---------------------------------------------------------------------------
template <int OUTF32>
__global__ __launch_bounds__(256) void gemm_bt_kernel(
    const bf16_t* __restrict__ A, const bf16_t* __restrict__ Bt,
    const float* __restrict__ bias, void* __restrict__ Cout,
    int M, int N, int K) {
  __shared__ __align__(16) bf16_t sA[2][128 * 32];
  __shared__ __align__(16) bf16_t sB[2][128 * 32];
  const int tid = threadIdx.x;
  const int l = tid & 63, w = tid >> 6;
  const int lr = l & 15, lg = l >> 4;
  const int m0 = blockIdx.y * 128, n0 = blockIdx.x * 128;
  const int wr = (w >> 1) * 64, wc = (w & 1) * 64;

  const int i0 = tid, i1 = tid + 256;
  const bf16_t* ga0 = A + (size_t)(m0 + (i0 >> 2)) * K + (i0 & 3) * 8;
  const bf16_t* ga1 = A + (size_t)(m0 + (i1 >> 2)) * K + (i1 & 3) * 8;
  const bf16_t* gb0 = Bt + (size_t)(n0 + (i0 >> 2)) * K + (i0 & 3) * 8;
  const bf16_t* gb1 = Bt + (size_t)(n0 + (i1 >> 2)) * K + (i1 & 3) * 8;

  f32x4 acc[4][4] = {};

  const int nk = K >> 5;
  // prologue: stage tile 0 into buf 0
  gload16(ga0, &sA[0][i0 * 8]);
  gload16(ga1, &sA[0][i1 * 8]);
  gload16(gb0, &sB[0][i0 * 8]);
  gload16(gb1, &sB[0][i1 * 8]);
  __syncthreads();

  int cur = 0;
  for (int kt = 0; kt < nk; ++kt) {
    if (kt + 1 < nk) {  // issue next-tile loads into the other buffer
      const int ko = (kt + 1) * 32;
      gload16(ga0 + ko, &sA[cur ^ 1][i0 * 8]);
      gload16(ga1 + ko, &sA[cur ^ 1][i1 * 8]);
      gload16(gb0 + ko, &sB[cur ^ 1][i0 * 8]);
      gload16(gb1 + ko, &sB[cur ^ 1][i1 * 8]);
    }
    bf16x8 af[4], bv[4];
#pragma unroll
    for (int mf = 0; mf < 4; ++mf)
      af[mf] = *(const bf16x8*)&sA[cur][(wr + mf * 16 + lr) * 32 + lg * 8];
#pragma unroll
    for (int nf = 0; nf < 4; ++nf)
      bv[nf] = *(const bf16x8*)&sB[cur][(wc + nf * 16 + lr) * 32 + lg * 8];
#pragma unroll
    for (int mf = 0; mf < 4; ++mf)
#pragma unroll
      for (int nf = 0; nf < 4; ++nf)
        acc[mf][nf] = __builtin_amdgcn_mfma_f32_16x16x32_bf16(af[mf], bv[nf], acc[mf][nf], 0, 0, 0);
    __syncthreads();  // drains vmcnt (staged loads) + joins readers
    cur ^= 1;
  }

#pragma unroll
  for (int mf = 0; mf < 4; ++mf) {
#pragma unroll
    for (int nf = 0; nf < 4; ++nf) {
      int col = n0 + wc + nf * 16 + lr;
      float bb = bias[col];
      int rowb = m0 + wr + mf * 16 + lg * 4;
#pragma unroll
      for (int r = 0; r < 4; ++r) {
        float v = acc[mf][nf][r] + bb;
        if constexpr (OUTF32)
          ((float*)Cout)[(size_t)(rowb + r) * N + col] = v;
        else
          ((bf16_t*)Cout)[(size_t)(rowb + r) * N + col] = (bf16_t)v;
      }
    }
  }
}

// ---------------------------------------------------------------------------
// Unified flash attention, barrier-free main loop.
// One wave = one 32-row q-tile. Balanced blocks: all 4 waves share nt.
// Swapped QK^T (mfma(K,Q)): lane owns q-row = lane&31. KVBLK=32.
// K prefetched one tile ahead (reg double-buffer). Raw-domain softmax
// (scale folded into exp2). Direct-from-global operands; P in registers.
// ---------------------------------------------------------------------------
__global__ __launch_bounds__(256, 2) void attn_kernel(
    const bf16_t* __restrict__ qkv,   // [4096][3072]
    const bf16_t* __restrict__ kkv,   // [1024][2048]
    const bf16_t* __restrict__ vTs,   // [64][64][1024]  self V^T
    const bf16_t* __restrict__ vTc,   // [64][64][256]   cross V^T
    bf16_t* __restrict__ obuf) {      // [8192][1024]
  __shared__ __align__(16) char swb[4][4096];

  const int tid = threadIdx.x;
  const int w = tid >> 6, l = tid & 63;
  const int ql = l & 31;
  const bool uhi = l >= 32;
  const int hi8 = uhi ? 8 : 0;
  const int kv4 = uhi ? 4 : 0;

  const int bid = blockIdx.x;
  const bool is_self = bid < 512;
  int qt, bh, nt;
  if (is_self) {  // heaviest blocks (qt=31) dispatch first
    qt = 31 - (bid >> 4);
    bh = ((bid & 15) << 2) + w;
    nt = qt + 1;
  } else {
    int cb = bid - 512;
    qt = cb >> 4;
    bh = ((cb & 15) << 2) + w;
    nt = 8;
  }
  const int b = bh >> 4, h = bh & 15;
  const int hcol = h * 64;
  const int q0 = qt * 32;

  const bf16_t* ksrc;
  const bf16_t* vsrc;
  int kstride, kvb, vlen, ooff;
  if (is_self) {
    ksrc = qkv + 1024 + hcol; kstride = 3072; kvb = b * 1024;
    vsrc = vTs + (size_t)bh * 64 * 1024; vlen = 1024; ooff = 0;
  } else {
    ksrc = kkv + hcol; kstride = 2048; kvb = b * 256;
    vsrc = vTc + (size_t)bh * 64 * 256; vlen = 256; ooff = 1024;
  }

  // Q fragments (B-operand): lane holds col q = ql, k = hd = ks*16 + hi8 + j
  const bf16_t* qrow = qkv + (size_t)(b * 1024 + q0 + ql) * 3072 + hcol + hi8;
  bf16x8 qf[4];
#pragma unroll
  for (int ks = 0; ks < 4; ++ks) qf[ks] = *(const bf16x8*)(qrow + ks * 16);

  float mcur = -1e30f, lcur = 0.f;  // mcur in RAW (pre-scale) units
  f32x16 oacc[2] = {};

  // prefetch K tile 0
  bf16x8 kf[4], nkf[4];
  {
    const bf16_t* kr = ksrc + (size_t)(kvb + ql) * kstride + hi8;
#pragma unroll
    for (int ks = 0; ks < 4; ++ks) kf[ks] = *(const bf16x8*)(kr + ks * 16);
  }

  for (int t = 0; t < nt; ++t) {
    const int kv0 = t * 32;
    // V^T fragments for tile t (issued early; consumed after softmax)
    bf16x8 vf[2][2];
#pragma unroll
    for (int mb = 0; mb < 2; ++mb)
#pragma unroll
      for (int ks = 0; ks < 2; ++ks)
        vf[mb][ks] = *(const bf16x8*)(vsrc + (size_t)(mb * 32 + ql) * vlen + kv0 + ks * 16 + hi8);
    // prefetch K tile t+1
    if (t + 1 < nt) {
      const bf16_t* kr = ksrc + (size_t)(kvb + kv0 + 32 + ql) * kstride + hi8;
#pragma unroll
      for (int ks = 0; ks < 4; ++ks) nkf[ks] = *(const bf16x8*)(kr + ks * 16);
    }

    // S^T = K @ Q^T : C col = q = ql, row = kv = (r&3)+8*(r>>2)+kv4
    f32x16 sa = {};
    __builtin_amdgcn_s_setprio(1);
#pragma unroll
    for (int ks = 0; ks < 4; ++ks)
      sa = __builtin_amdgcn_mfma_f32_32x32x16_bf16(kf[ks], qf[ks], sa, 0, 0, 0);
    __builtin_amdgcn_s_setprio(0);

    float sv[16];
    const bool mt = is_self && (t == qt);  // diagonal tile
#pragma unroll
    for (int r = 0; r < 16; ++r) {
      float v = sa[r];
      if (mt) {
        int kvr = (r & 3) + 8 * (r >> 2) + kv4;
        v = (kvr > ql) ? -1e30f : v;
      }
      sv[r] = v;  // RAW units
    }
    float tm = fmaxf(
        fmaxf(fmaxf(fmaxf(sv[0], sv[1]), fmaxf(sv[2], sv[3])),
              fmaxf(fmaxf(sv[4], sv[5]), fmaxf(sv[6], sv[7]))),
        fmaxf(fmaxf(fmaxf(sv[8], sv[9]), fmaxf(sv[10], sv[11])),
              fmaxf(fmaxf(sv[12], sv[13]), fmaxf(sv[14], sv[15]))));
    tm = fmaxf(tm, __shfl_xor(tm, 32));

    if (!__all(tm <= mcur + 64.f)) {  // defer-max (64 raw = 8 scaled)
      float mn = fmaxf(mcur, tm);
      float sc = FEXP2((mcur - mn) * EXP2C);
      mcur = mn;
      lcur *= sc;
#pragma unroll
      for (int mb = 0; mb < 2; ++mb)
#pragma unroll
        for (int r = 0; r < 16; ++r) oacc[mb][r] *= sc;
    }

    const float hm = mcur * EXP2C;
    float pf[16];
#pragma unroll
    for (int r = 0; r < 16; ++r) pf[r] = FEXP2(__builtin_fmaf(sv[r], EXP2C, -hm));
    float ps = (((pf[0] + pf[1]) + (pf[2] + pf[3])) + ((pf[4] + pf[5]) + (pf[6] + pf[7]))) +
               (((pf[8] + pf[9]) + (pf[10] + pf[11])) + ((pf[12] + pf[13]) + (pf[14] + pf[15])));
    ps += __shfl_xor(ps, 32);
    lcur += ps;

    // P -> PV B-fragments, in-register (pack + half-wave exchange + select)
    unsigned o01 = pkbf(pf[0], pf[1]), o23 = pkbf(pf[2], pf[3]);
    unsigned o45 = pkbf(pf[4], pf[5]), o67 = pkbf(pf[6], pf[7]);
    unsigned o89 = pkbf(pf[8], pf[9]), o1011 = pkbf(pf[10], pf[11]);
    unsigned o1213 = pkbf(pf[12], pf[13]), o1415 = pkbf(pf[14], pf[15]);
    unsigned p01 = __shfl_xor(o01, 32), p23 = __shfl_xor(o23, 32);
    unsigned p45 = __shfl_xor(o45, 32), p67 = __shfl_xor(o67, 32);
    unsigned p89 = __shfl_xor(o89, 32), p1011 = __shfl_xor(o1011, 32);
    unsigned p1213 = __shfl_xor(o1213, 32), p1415 = __shfl_xor(o1415, 32);
    uint4 w0 = { uhi ? p45 : o01, uhi ? p67 : o23, uhi ? o45 : p01, uhi ? o67 : p23 };
    uint4 w1 = { uhi ? p1213 : o89, uhi ? p1415 : o1011, uhi ? o1213 : p89, uhi ? o1415 : p1011 };
    bf16x8 pb0 = __builtin_bit_cast(bf16x8, w0);
    bf16x8 pb1 = __builtin_bit_cast(bf16x8, w1);

    // O^T += V^T @ P : C col = q = ql, row = hd
    __builtin_amdgcn_s_setprio(1);
#pragma unroll
    for (int mb = 0; mb < 2; ++mb) {
      oacc[mb] = __builtin_amdgcn_mfma_f32_32x32x16_bf16(vf[mb][0], pb0, oacc[mb], 0, 0, 0);
      oacc[mb] = __builtin_amdgcn_mfma_f32_32x32x16_bf16(vf[mb][1], pb1, oacc[mb], 0, 0, 0);
    }
    __builtin_amdgcn_s_setprio(0);

    if (t + 1 < nt) {
#pragma unroll
      for (int ks = 0; ks < 4; ++ks) kf[ks] = nkf[ks];
    }
  }

  // epilogue: normalize, transpose O^T -> O via per-wave LDS, coalesced store
  const float rl = 1.0f / lcur;
  char* swp = &swb[w][0];
#pragma unroll
  for (int mb = 0; mb < 2; ++mb)
#pragma unroll
    for (int r2 = 0; r2 < 8; ++r2) {
      float lo = oacc[mb][2 * r2] * rl;
      float hiv = oacc[mb][2 * r2 + 1] * rl;
      int hdb = (r2 & 1) * 2 + 8 * (r2 >> 1) + kv4 + mb * 32;
      int off = (ql * 128 + hdb * 2) ^ ((ql & 7) << 4);
      *(unsigned*)(swp + off) = pkbf(lo, hiv);
    }
  __syncthreads();
  const int orow = b * 2048 + ooff + q0;
#pragma unroll
  for (int it = 0; it < 4; ++it) {
    int idx = it * 64 + l;
    int q = idx >> 3, ch = idx & 7;
    int off = (q * 128 + ch * 16) ^ ((q & 7) << 4);
    uint4 d = *(uint4*)(swp + off);
    *(uint4*)&obuf[(size_t)(orow + q) * 1024 + hcol + ch * 8] = d;
  }
}

// ---------------------------------------------------------------------------
extern "C" void kernel_launch(void* const* d_in, const int* in_sizes, int n_in,
                              void* d_out, int out_size, void* d_ws, size_t ws_size,
                              hipStream_t stream) {
  (void)in_sizes; (void)n_in; (void)out_size; (void)ws_size;
  const float* x   = (const float*)d_in[0];
  const float* pkg = (const float*)d_in[1];
  const float* Wc  = (const float*)d_in[2];
  const float* bc  = (const float*)d_in[3];
  const float* Wk  = (const float*)d_in[4];
  const float* bk  = (const float*)d_in[5];
  const float* Wp  = (const float*)d_in[6];
  const float* bp  = (const float*)d_in[7];
  float* out = (float*)d_out;

  char* ws = (char*)d_ws;
  const size_t MB = 1u << 20;
  bf16_t* xb   = (bf16_t*)(ws + 0 * MB);   // [4096][1024]   8 MB
  bf16_t* pkb  = (bf16_t*)(ws + 8 * MB);   // [1024][1024]   2 MB
  bf16_t* Wct  = (bf16_t*)(ws + 10 * MB);  // [3072][1024]   6 MB
  bf16_t* Wkt  = (bf16_t*)(ws + 16 * MB);  // [2048][1024]   4 MB
  bf16_t* Wpt  = (bf16_t*)(ws + 20 * MB);  // [1024][1024]   2 MB
  bf16_t* kkvb = (bf16_t*)(ws + 22 * MB);  // [1024][2048]   4 MB
  bf16_t* abuf = (bf16_t*)(ws + 26 * MB);  // [8192][1024]  16 MB
  bf16_t* vTc  = (bf16_t*)(ws + 42 * MB);  // [64][64][256]  2 MB (ws total 44 MB)
  // d_out double-duty: qkv intermediate + self V^T; both dead before proj GEMM
  bf16_t* qkvb = (bf16_t*)d_out;                      // [4096][3072] 24 MB
  bf16_t* vTs  = (bf16_t*)((char*)d_out + 24 * MB);   // [64][64][1024] 8 MB

  cvt_kernel<<<4096, 256, 0, stream>>>(x, xb, 4096 * 1024 / 4);
  cvt_kernel<<<1024, 256, 0, stream>>>(pkg, pkb, 1024 * 1024 / 4);
  tcvt_kernel<<<dim3(3072 / 32, 1024 / 32), 256, 0, stream>>>(Wc, Wct, 1024, 3072);
  tcvt_kernel<<<dim3(2048 / 32, 1024 / 32), 256, 0, stream>>>(Wk, Wkt, 1024, 2048);
  tcvt_kernel<<<dim3(1024 / 32, 1024 / 32), 256, 0, stream>>>(Wp, Wpt, 1024, 1024);

  gemm_bt_kernel<0><<<dim3(24, 32), 256, 0, stream>>>(xb, Wct, bc, qkvb, 4096, 3072, 1024);
  gemm_bt_kernel<0><<<dim3(16, 8), 256, 0, stream>>>(pkb, Wkt, bk, kkvb, 1024, 2048, 1024);

  vtrans_kernel<<<dim3(16, 64), 256, 0, stream>>>(qkvb, vTs, 1024, 3072, 2048);
  vtrans_kernel<<<dim3(4, 64), 256, 0, stream>>>(kkvb, vTc, 256, 2048, 1024);

  attn_kernel<<<dim3(1024), 256, 0, stream>>>(qkvb, kkvb, vTs, vTc, abuf);

  gemm_bt_kernel<1><<<dim3(8, 64), 256, 0, stream>>>(abuf, Wpt, bp, out, 8192, 1024, 1024);
}